// Round 10
// baseline (194.713 us; speedup 1.0000x reference)
//
#include <hip/hip_runtime.h>
#include <math.h>

typedef int i32x4 __attribute__((ext_vector_type(4)));
typedef int i32x16 __attribute__((ext_vector_type(16)));

#define NT_M 128   // T/64
#define NT_D 32    // D/64
#define NT_F 22    // F/64
#define DDIM 2048
#define FDIM 1408

// Fragment-order byte offset of element (r,k) in a 64x64 i8 tile (4096B).
// Layout = [k-block(2)][row-half(2)][k-halfword(2)][row%32(32)][k%16(16)]
// so an MFMA fragment read is base + kkblk*2048 + rowhalf*1024 + lane*16:
// canonical stride-16 per lane -> zero bank conflicts, and staging stays linear.
#define OFFN(r, k)                                                                  \
  (((((k) >> 5)) << 11) + ((((r) >> 5)) << 10) + (((((k) >> 4) & 1)) << 9) +        \
   ((((r) & 31)) << 4) + ((k) & 15))

__device__ __forceinline__ void gld_lds16(const void* gp, void* lp) {
  auto* l = reinterpret_cast<unsigned int __attribute__((address_space(3)))*>(
      (unsigned int)(unsigned long long)(lp));
  const auto* g = reinterpret_cast<const unsigned int __attribute__((address_space(1)))*>(
      (unsigned long long)(gp));
  __builtin_amdgcn_global_load_lds(g, l, 16, 0, 0);
}

__device__ __forceinline__ i32x16 zero16() {
  i32x16 z;
#pragma unroll
  for (int e = 0; e < 16; ++e) z[e] = 0;
  return z;
}

// ---------------- pack x into 3 signed base-256 digit planes, fragment-order tiles ----------------
__global__ __launch_bounds__(256) void pack_x_kernel(const int* __restrict__ x,
                                                     signed char* __restrict__ XD) {
  const int tk = blockIdx.x;   // 0..31   (D tiles)
  const int tm = blockIdx.y;   // 0..127  (T tiles)
  const int tid = threadIdx.x;
  signed char* tile = XD + (size_t)(tm * NT_D + tk) * 3 * 4096;
  const int* base = x + (size_t)tm * 64 * DDIM + tk * 64;
#pragma unroll
  for (int i = 0; i < 4; ++i) {
    const int gi = i * 256 + tid;      // 1024 groups of 4 elements
    const int row = gi >> 4;           // 64 rows
    const int k4 = (gi & 15) << 2;     // k offset, multiple of 4
    const i32x4 v = *(const i32x4*)(base + (size_t)row * DDIM + k4);
    unsigned p0 = 0, p1 = 0, p2 = 0;
#pragma unroll
    for (int j = 0; j < 4; ++j) {
      const int val = v[j];
      const int b0 = (int)(signed char)(val & 0xff);
      const int c = (val - b0) >> 8;
      const int b1 = (int)(signed char)(c & 0xff);
      const int b2 = (c - b1) >> 8;
      p0 |= ((unsigned)(val & 0xff)) << (8 * j);
      p1 |= ((unsigned)(c & 0xff)) << (8 * j);
      p2 |= ((unsigned)(b2 & 0xff)) << (8 * j);
    }
    const int off = OFFN(row, k4);
    *(unsigned*)(tile + off) = p0;
    *(unsigned*)(tile + 4096 + off) = p1;
    *(unsigned*)(tile + 8192 + off) = p2;
  }
}

// ---------------- pack w1/w3/w2 (int32 holding i8 values) into fragment-order tiles ----------------
__global__ __launch_bounds__(256) void pack_w_kernel(const int* __restrict__ w1,
                                                     const int* __restrict__ w3,
                                                     const int* __restrict__ w2,
                                                     signed char* __restrict__ W1T,
                                                     signed char* __restrict__ W3T,
                                                     signed char* __restrict__ W2T) {
  const int which = blockIdx.y;   // 0=w1, 1=w3, 2=w2
  const int t = blockIdx.x;       // 704 tiles each
  const int tid = threadIdx.x;
  const int* src;
  signed char* dst;
  int rowstride, nk;
  if (which == 0)      { src = w1; dst = W1T; rowstride = DDIM; nk = NT_D; }
  else if (which == 1) { src = w3; dst = W3T; rowstride = DDIM; nk = NT_D; }
  else                 { src = w2; dst = W2T; rowstride = FDIM; nk = NT_F; }
  const int tr = t / nk, tk = t % nk;
  signed char* tile = dst + (size_t)t * 4096;
  const int* base = src + (size_t)tr * 64 * rowstride + tk * 64;
#pragma unroll
  for (int i = 0; i < 4; ++i) {
    const int gi = i * 256 + tid;
    const int row = gi >> 4;
    const int k4 = (gi & 15) << 2;
    const i32x4 v = *(const i32x4*)(base + (size_t)row * rowstride + k4);
    const unsigned p = ((unsigned)(v[0] & 0xff)) | ((unsigned)(v[1] & 0xff) << 8) |
                       ((unsigned)(v[2] & 0xff) << 16) | ((unsigned)(v[3] & 0xff) << 24);
    *(unsigned*)(tile + OFFN(row, k4)) = p;
  }
}

// ---------------- gemm1: 64x128 tile, 4 waves (2x2), OFFN conflict-free, 2-buf LDS ----------------
// Per wave per kk: 3 A + 4 B fragment reads feed 12 MFMAs (LDS:MFMA = 0.58).
// r1=(x@w1^T)>>s1, r2=(x@w3^T)>>s3, gate=(silu_q23(r1)*r2)>>23  (exact int64 semantics)
__global__ __launch_bounds__(256, 2) void gemm1_kernel(
    const signed char* __restrict__ XD, const signed char* __restrict__ W1T,
    const signed char* __restrict__ W3T, signed char* __restrict__ GATE,
    const int* __restrict__ scale1p, const int* __restrict__ scale3p) {
  __shared__ __align__(16) signed char lds[57344];  // A: 2x12288 @0, B: 2x16384 @24576
  const int tid = threadIdx.x;
  const int wv = tid >> 6;   // 0..3
  const int lane = tid & 63;
  const int r32 = lane & 31;
  const int g = lane >> 5;
  // XCD-grouping swizzle: all 11 F-blocks of one tm land on the same XCD.
  // 1408 blocks = 8 XCD * 16 groups * 11 tfb; bijective.
  const int bi = blockIdx.x;
  const int c = bi & 7;
  const int q = bi >> 3;            // 0..175
  const int tm = (q / 11) * 8 + c;  // 0..127 (64-row tile)
  const int tfb = q % 11;           // 0..10  (128-col F block)
  const int wm = wv >> 1, wn = wv & 1;  // wm: 32-row strip, wn: 64-col F-subtile

  // acc[mat][nf][plane]
  i32x16 a10p0 = zero16(), a10p1 = zero16(), a10p2 = zero16();
  i32x16 a11p0 = zero16(), a11p1 = zero16(), a11p2 = zero16();
  i32x16 a30p0 = zero16(), a30p1 = zero16(), a30p2 = zero16();
  i32x16 a31p0 = zero16(), a31p1 = zero16(), a31p2 = zero16();

  const signed char* srcA = XD + (size_t)tm * NT_D * 12288;

  auto stage = [&](int kt, int b) {
    signed char* bufA = lds + b * 12288;
    signed char* bufB = lds + 24576 + b * 16384;
#pragma unroll
    for (int j = 0; j < 3; ++j) {
      const int ch = wv * 3 + j;  // 12 chunks: 3 digit planes x 4KB
      gld_lds16(srcA + (size_t)kt * 12288 + ch * 1024 + lane * 16, bufA + ch * 1024);
    }
#pragma unroll
    for (int j = 0; j < 4; ++j) {
      const int ch = wv * 4 + j;       // 16 chunks: [mat(2)][fsub(2)][qt(4)]
      const int mat = ch >> 3;
      const int fsub = (ch >> 2) & 1;
      const int qt = ch & 3;
      const signed char* s = (mat ? W3T : W1T) +
                             (size_t)((tfb * 2 + fsub) * NT_D + kt) * 4096 + qt * 1024 +
                             lane * 16;
      gld_lds16(s, bufB + ch * 1024);
    }
  };

  stage(0, 0);

  // Canonical fragment addresses (stride-16 per lane, zero conflicts).
  const int aoff = (wm << 10) + lane * 16;   // rowhalf = wm
  const int loff = lane * 16;

  for (int kt = 0; kt < NT_D; ++kt) {
    const int b = kt & 1;
    __syncthreads();  // drains vmcnt(0): buffer b ready
    if (kt + 1 < NT_D) stage(kt + 1, b ^ 1);
    const signed char* A = lds + b * 12288;
    const signed char* Bb = lds + 24576 + b * 16384 + wn * 4096;  // fsub = wn
#pragma unroll
    for (int kk = 0; kk < 2; ++kk) {
      const int ko = kk * 2048;
      const i32x4 a0 = *(const i32x4*)(A + ko + aoff);
      const i32x4 a1 = *(const i32x4*)(A + 4096 + ko + aoff);
      const i32x4 a2 = *(const i32x4*)(A + 8192 + ko + aoff);
      {  // nf = 0 (rowhalf 0 of B tiles)
        const i32x4 bb1 = *(const i32x4*)(Bb + ko + loff);
        const i32x4 bb3 = *(const i32x4*)(Bb + 8192 + ko + loff);
        a10p0 = __builtin_amdgcn_mfma_i32_32x32x32_i8(a0, bb1, a10p0, 0, 0, 0);
        a10p1 = __builtin_amdgcn_mfma_i32_32x32x32_i8(a1, bb1, a10p1, 0, 0, 0);
        a10p2 = __builtin_amdgcn_mfma_i32_32x32x32_i8(a2, bb1, a10p2, 0, 0, 0);
        a30p0 = __builtin_amdgcn_mfma_i32_32x32x32_i8(a0, bb3, a30p0, 0, 0, 0);
        a30p1 = __builtin_amdgcn_mfma_i32_32x32x32_i8(a1, bb3, a30p1, 0, 0, 0);
        a30p2 = __builtin_amdgcn_mfma_i32_32x32x32_i8(a2, bb3, a30p2, 0, 0, 0);
      }
      {  // nf = 1 (rowhalf 1)
        const i32x4 bb1 = *(const i32x4*)(Bb + 1024 + ko + loff);
        const i32x4 bb3 = *(const i32x4*)(Bb + 8192 + 1024 + ko + loff);
        a11p0 = __builtin_amdgcn_mfma_i32_32x32x32_i8(a0, bb1, a11p0, 0, 0, 0);
        a11p1 = __builtin_amdgcn_mfma_i32_32x32x32_i8(a1, bb1, a11p1, 0, 0, 0);
        a11p2 = __builtin_amdgcn_mfma_i32_32x32x32_i8(a2, bb1, a11p2, 0, 0, 0);
        a31p0 = __builtin_amdgcn_mfma_i32_32x32x32_i8(a0, bb3, a31p0, 0, 0, 0);
        a31p1 = __builtin_amdgcn_mfma_i32_32x32x32_i8(a1, bb3, a31p1, 0, 0, 0);
        a31p2 = __builtin_amdgcn_mfma_i32_32x32x32_i8(a2, bb3, a31p2, 0, 0, 0);
      }
    }
  }

  const int s1v = scale1p[0];
  const int s3v = scale3p[0];
  const double QINV = 1.0 / 8388608.0;
  const int f64 = tfb * 2 + wn;
  signed char* gt = GATE + (size_t)(tm * NT_F + f64) * 4096;
#pragma unroll
  for (int nf = 0; nf < 2; ++nf) {
    // OFFN(ml, colf): ml = wm*32+rowe, colf = nf*32+r32
    const int ebase = (nf << 11) + (wm << 10) + ((r32 >> 4) << 9) + (r32 & 15);
    const i32x16& p10 = nf ? a11p0 : a10p0;
    const i32x16& p11 = nf ? a11p1 : a10p1;
    const i32x16& p12 = nf ? a11p2 : a10p2;
    const i32x16& p30 = nf ? a31p0 : a30p0;
    const i32x16& p31 = nf ? a31p1 : a30p1;
    const i32x16& p32 = nf ? a31p2 : a30p2;
#pragma unroll
    for (int e = 0; e < 16; ++e) {
      const int rowe = (e & 3) + 8 * (e >> 2) + 4 * g;
      const long long av1 =
          (long long)p10[e] + ((long long)p11[e] << 8) + ((long long)p12[e] << 16);
      const long long r1 = av1 >> s1v;
      const long long av3 =
          (long long)p30[e] + ((long long)p31[e] << 8) + ((long long)p32[e] << 16);
      const long long r2 = av3 >> s3v;
      // Exact silu: |r1| <= 2^14 so |xf| <= 2^-9; sigma = 0.5 + xf/4 - xf^3/48,
      // truncation < 6e-17 (< 1 ulp of 0.5) -- exceeds the accuracy of the libm
      // exp path already verified bit-exact (rint margin ~4e-8).
      const double xf = (double)r1 * QINV;
      const double x2 = xf * xf;
      const double sg = 0.5 + xf * (0.25 - x2 * (1.0 / 48.0));
      const long long s1q = (long long)rint((double)r1 * sg);
      const long long gv = (s1q * r2) >> 23;
      gt[ebase + rowe * 16] = (signed char)gv;
    }
  }
}

// ---------------- gemm2: q = (gate @ w2^T) >> s2, int32 out; 2-buf, conflict-free reads ----------------
__global__ __launch_bounds__(256, 2) void gemm2_kernel(
    const signed char* __restrict__ GATE, const signed char* __restrict__ W2T,
    int* __restrict__ out, const int* __restrict__ scale2p) {
  __shared__ __align__(16) signed char lds[32768];  // 2 bufs x (A 8192 + B 8192)
  const int tid = threadIdx.x;
  const int wv = tid >> 6;
  const int lane = tid & 63;
  const int r32 = lane & 31;
  const int g = lane >> 5;
  // XCD-grouping swizzle: 1024 blocks = 8 XCDs * 8 tm * 16 tn
  const int bi = blockIdx.x;
  const int c = bi & 7;
  const int q = bi >> 3;           // 0..127
  const int tm = (q >> 4) * 8 + c; // 0..63 (T/128)
  const int tn = q & 15;           // 0..15 (D/128)
  const int wm = wv >> 1, wn = wv & 1;

  i32x16 acc00 = zero16(), acc01 = zero16(), acc10 = zero16(), acc11 = zero16();

  auto stage = [&](int kt, int b) {
    signed char* buf = lds + b * 16384;
#pragma unroll
    for (int j = 0; j < 2; ++j) {
      const int ch = wv * 2 + j;  // 8 chunks: 2 gate m-tiles
      gld_lds16(GATE + ((size_t)((tm * 2 + (ch >> 2)) * NT_F + kt)) * 4096 + (ch & 3) * 1024 +
                    lane * 16,
                buf + ch * 1024);
    }
#pragma unroll
    for (int j = 0; j < 2; ++j) {
      const int ch = wv * 2 + j;  // 8 chunks: 2 w2 d-tiles
      gld_lds16(W2T + ((size_t)((tn * 2 + (ch >> 2)) * NT_F + kt)) * 4096 + (ch & 3) * 1024 +
                    lane * 16,
                buf + 8192 + ch * 1024);
    }
  };

  const int loff = lane * 16;

  auto compute = [&](int b) {
    const signed char* A = lds + b * 16384 + wm * 4096;
    const signed char* B = lds + b * 16384 + 8192 + wn * 4096;
#pragma unroll
    for (int kk = 0; kk < 2; ++kk) {
      const int ko = kk * 2048;
      const i32x4 a0 = *(const i32x4*)(A + ko + loff);          // rows 0-31 of wave tile
      const i32x4 a1 = *(const i32x4*)(A + ko + 1024 + loff);   // rows 32-63
      const i32x4 b0 = *(const i32x4*)(B + ko + loff);
      const i32x4 b1 = *(const i32x4*)(B + ko + 1024 + loff);
      acc00 = __builtin_amdgcn_mfma_i32_32x32x32_i8(a0, b0, acc00, 0, 0, 0);
      acc01 = __builtin_amdgcn_mfma_i32_32x32x32_i8(a0, b1, acc01, 0, 0, 0);
      acc10 = __builtin_amdgcn_mfma_i32_32x32x32_i8(a1, b0, acc10, 0, 0, 0);
      acc11 = __builtin_amdgcn_mfma_i32_32x32x32_i8(a1, b1, acc11, 0, 0, 0);
    }
  };

  stage(0, 0);

  for (int kt = 0; kt < NT_F; ++kt) {
    const int b = kt & 1;
    __syncthreads();
    if (kt + 1 < NT_F) stage(kt + 1, b ^ 1);
    compute(b);
  }

  const int s2v = scale2p[0];
  int* obase = out + (size_t)(tm * 128 + wm * 64) * DDIM + tn * 128 + wn * 64;
#pragma unroll
  for (int e = 0; e < 16; ++e) {
    const int rowe = (e & 3) + 8 * (e >> 2) + 4 * g;
    obase[(size_t)rowe * DDIM + r32] = acc00[e] >> s2v;
    obase[(size_t)rowe * DDIM + 32 + r32] = acc01[e] >> s2v;
    obase[(size_t)(rowe + 32) * DDIM + r32] = acc10[e] >> s2v;
    obase[(size_t)(rowe + 32) * DDIM + 32 + r32] = acc11[e] >> s2v;
  }
}

extern "C" void kernel_launch(void* const* d_in, const int* in_sizes, int n_in,
                              void* d_out, int out_size, void* d_ws, size_t ws_size,
                              hipStream_t stream) {
  if (n_in < 7) return;
  const int* x = (const int*)d_in[0];
  const int* w1 = (const int*)d_in[1];
  const int* w2 = (const int*)d_in[2];
  const int* w3 = (const int*)d_in[3];
  const int* s1 = (const int*)d_in[4];
  const int* s2 = (const int*)d_in[5];
  const int* s3 = (const int*)d_in[6];
  signed char* ws = (signed char*)d_ws;
  int* out = (int*)d_out;

  const size_t XD_OFF = 0;
  const size_t XD_SZ = (size_t)NT_M * NT_D * 3 * 4096;   // 50331648
  const size_t WT_SZ = (size_t)NT_F * NT_D * 4096;       // 2883584
  const size_t W1_OFF = XD_OFF + XD_SZ;
  const size_t W3_OFF = W1_OFF + WT_SZ;
  const size_t W2_OFF = W3_OFF + WT_SZ;
  const size_t GATE_OFF = W2_OFF + WT_SZ;
  const size_t GATE_SZ = (size_t)NT_M * NT_F * 4096;     // 11534336
  if (ws_size < GATE_OFF + GATE_SZ) return;  // ~70.5 MB required

  pack_x_kernel<<<dim3(NT_D, NT_M), 256, 0, stream>>>(x, ws + XD_OFF);
  pack_w_kernel<<<dim3(704, 3), 256, 0, stream>>>(w1, w3, w2, ws + W1_OFF, ws + W3_OFF,
                                                  ws + W2_OFF);
  gemm1_kernel<<<dim3(1408), 256, 0, stream>>>(ws + XD_OFF, ws + W1_OFF, ws + W3_OFF,
                                               ws + GATE_OFF, s1, s3);
  gemm2_kernel<<<dim3(1024), 256, 0, stream>>>(ws + GATE_OFF, ws + W2_OFF, out, s2);
}